// Round 2
// baseline (112.175 us; speedup 1.0000x reference)
//
#include <hip/hip_runtime.h>

// out[b,c,l] = sum_r x[b,r,l] * weight[idx[b,l], r, c] + bias[idx[b,l], c]
//   x:       (4, 256, 32, 32) fp32   flat (b*256 + r)*1024 + l
//   indexes: (4096,) int             j in [0,8)
//   weight:  (8, 256, 256) fp32      (j*256 + r)*256 + c
//   bias:    (8, 256) fp32
//   out:     (4, 256, 32, 32) fp32   (b*256 + c)*1024 + l
//
// Pipeline: bucket tokens by j -> transpose x to (tok, r) -> 8 bucketed GEMMs
// (tile 32 tok x 64 c, K=256) writing (tok, c) -> transpose to (b, c, l).
// Kills the 1 GB L2 weight stream of the per-token version (weight read
// ~34 MB total) and makes every global access coalesced.

#define N_TOK   4096
#define R_MAX   256
#define C_DIM   256
#define N_J     8
#define MT      32      // tokens per GEMM block
#define NT      64      // channels per GEMM block
#define KC      16      // K chunk

// Scratch in module globals (avoids ws_size assumptions). Rewritten fully
// on every call — no cross-call state.
__device__ float g_xt[N_TOK * R_MAX];        // 4 MB  (tok, r)
__device__ float g_outtmp[N_TOK * C_DIM];    // 4 MB  (tok, c)
__device__ int   g_perm[N_J * N_TOK];        // 128 KB, 8 oversized buckets
__device__ int   g_cnt[N_J];

// ---------------- Kernel A: bucket tokens by index ----------------
__global__ __launch_bounds__(1024) void bucket_kernel(const int* __restrict__ idx)
{
    __shared__ int cur_s[N_J];
    const int t = threadIdx.x;
    if (t < N_J) cur_s[t] = 0;
    __syncthreads();

    #pragma unroll
    for (int i = 0; i < N_TOK / 1024; ++i) {
        const int tok = t + i * 1024;
        const int j   = idx[tok];
        const int pos = atomicAdd(&cur_s[j], 1);
        g_perm[j * N_TOK + pos] = tok;
    }
    __syncthreads();
    if (t < N_J) g_cnt[t] = cur_s[t];
}

// ---------------- Kernel B: x (b,r,l) -> xt (tok, r) ----------------
// grid (16 l-tiles, 4 r-tiles, 4 b), block 256, 64x64 tiles.
__global__ __launch_bounds__(256) void xpose_kernel(const float* __restrict__ x)
{
    __shared__ float T[64 * 65];
    const int t  = threadIdx.x;
    const int l0 = blockIdx.x * 64;
    const int r0 = blockIdx.y * 64;
    const int b  = blockIdx.z;

    const int lane_lo = t & 63;   // contiguous within wave
    const int grp     = t >> 6;   // 0..3

    #pragma unroll
    for (int i = 0; i < 16; ++i) {
        const int rl = i * 4 + grp;         // local r
        const int ll = lane_lo;             // local l (coalesced read)
        T[rl * 65 + ll] = x[((b << 8) + r0 + rl) * 1024 + l0 + ll];
    }
    __syncthreads();
    #pragma unroll
    for (int i = 0; i < 16; ++i) {
        const int ll = i * 4 + grp;         // local l
        const int rl = lane_lo;             // local r (coalesced write)
        g_xt[((b << 10) + l0 + ll) * R_MAX + r0 + rl] = T[rl * 65 + ll];
    }
}

// ---------------- Kernel C: bucketed GEMM ----------------
// grid (4 c-tiles, 128 tok-tiles, 8 j), block 256.
// Out[32 tok x 64 c] = Xt[32 x 256] @ W_j[256 x 64] + bias_j
__global__ __launch_bounds__(256) void gemm_kernel(const float* __restrict__ weight,
                                                   const float* __restrict__ bias)
{
    const int j     = blockIdx.z;
    const int tile  = blockIdx.y;
    const int cb    = blockIdx.x * NT;
    const int cnt_j = g_cnt[j];
    const int start = tile * MT;
    if (start >= cnt_j) return;
    const int rows = min(MT, cnt_j - start);

    __shared__ int   rowtok[MT];
    __shared__ float As[KC][36];   // [k][tok], +4 pad: 16B-aligned rows, bank rotate
    __shared__ float Bs[KC][68];   // [k][c],  +4 pad

    const int t = threadIdx.x;
    if (t < MT) rowtok[t] = g_perm[j * N_TOK + start + min(t, rows - 1)];
    __syncthreads();

    const int tx = t & 15;        // c group (4 cols)
    const int ty = t >> 4;        // token group (2 rows)

    float acc0x = 0.f, acc0y = 0.f, acc0z = 0.f, acc0w = 0.f;
    float acc1x = 0.f, acc1y = 0.f, acc1z = 0.f, acc1w = 0.f;

    const float* __restrict__ wj = weight + j * (R_MAX * C_DIM) + cb;

    for (int k0 = 0; k0 < R_MAX; k0 += KC) {
        // Stage A: 32 rows x 16 k = 128 float4 loads (rows contiguous 64B)
        if (t < 128) {
            const int r   = t >> 2;
            const int seg = t & 3;
            const float4 v = *(const float4*)(g_xt + rowtok[r] * R_MAX + k0 + seg * 4);
            As[seg * 4 + 0][r] = v.x;
            As[seg * 4 + 1][r] = v.y;
            As[seg * 4 + 2][r] = v.z;
            As[seg * 4 + 3][r] = v.w;
        }
        // Stage B: 16 k x 64 c = 256 float4 loads (fully coalesced)
        {
            const int kk = t >> 4;
            const int c4 = (t & 15) * 4;
            *(float4*)&Bs[kk][c4] = *(const float4*)(wj + (k0 + kk) * C_DIM + c4);
        }
        __syncthreads();

        #pragma unroll
        for (int kk = 0; kk < KC; ++kk) {
            const float2 a = *(const float2*)&As[kk][ty * 2];
            const float4 b4 = *(const float4*)&Bs[kk][tx * 4];
            acc0x += a.x * b4.x; acc0y += a.x * b4.y;
            acc0z += a.x * b4.z; acc0w += a.x * b4.w;
            acc1x += a.y * b4.x; acc1y += a.y * b4.y;
            acc1z += a.y * b4.z; acc1w += a.y * b4.w;
        }
        __syncthreads();
    }

    const float4 bb = *(const float4*)(bias + j * C_DIM + cb + tx * 4);
    {
        const int r = ty * 2;
        if (r < rows) {
            float4 o; o.x = acc0x + bb.x; o.y = acc0y + bb.y;
            o.z = acc0z + bb.z; o.w = acc0w + bb.w;
            *(float4*)(g_outtmp + rowtok[r] * C_DIM + cb + tx * 4) = o;
        }
        if (r + 1 < rows) {
            float4 o; o.x = acc1x + bb.x; o.y = acc1y + bb.y;
            o.z = acc1z + bb.z; o.w = acc1w + bb.w;
            *(float4*)(g_outtmp + rowtok[r + 1] * C_DIM + cb + tx * 4) = o;
        }
    }
}

// ---------------- Kernel D: outtmp (tok,c) -> out (b,c,l) ----------------
// grid (16 l-tiles, 4 c-tiles, 4 b), block 256.
__global__ __launch_bounds__(256) void opose_kernel(float* __restrict__ out)
{
    __shared__ float T[64 * 65];
    const int t  = threadIdx.x;
    const int l0 = blockIdx.x * 64;
    const int c0 = blockIdx.y * 64;
    const int b  = blockIdx.z;

    const int lane_lo = t & 63;
    const int grp     = t >> 6;

    #pragma unroll
    for (int i = 0; i < 16; ++i) {
        const int ll = i * 4 + grp;
        const int cl = lane_lo;             // coalesced read over c
        T[ll * 65 + cl] = g_outtmp[((b << 10) + l0 + ll) * C_DIM + c0 + cl];
    }
    __syncthreads();
    #pragma unroll
    for (int i = 0; i < 16; ++i) {
        const int cl = i * 4 + grp;
        const int ll = lane_lo;             // coalesced write over l
        out[((b << 8) + c0 + cl) * 1024 + l0 + ll] = T[ll * 65 + cl];
    }
}

extern "C" void kernel_launch(void* const* d_in, const int* in_sizes, int n_in,
                              void* d_out, int out_size, void* d_ws, size_t ws_size,
                              hipStream_t stream)
{
    const float* x      = (const float*)d_in[0];
    const int*   idx    = (const int*)  d_in[1];
    const float* weight = (const float*)d_in[2];
    const float* bias   = (const float*)d_in[3];
    float*       out    = (float*)      d_out;

    bucket_kernel<<<1, 1024, 0, stream>>>(idx);
    xpose_kernel<<<dim3(16, 4, 4), 256, 0, stream>>>(x);
    gemm_kernel<<<dim3(4, N_TOK / MT, N_J), 256, 0, stream>>>(weight, bias);
    opose_kernel<<<dim3(16, 4, 4), 256, 0, stream>>>(out);
}